// Round 1
// baseline (2306.524 us; speedup 1.0000x reference)
//
#include <hip/hip_runtime.h>
#include <math.h>

#define N 768
#define IN_DIM 128
#define HID 256
#define HEADS 8
#define HD 32
#define TJ 16
#define NT (N / TJ)

__device__ __forceinline__ float relu_f(float x) { return fmaxf(x, 0.f); }

// ---------------------------------------------------------------------------
// prep: Q = x@Wq+bq, K = x@Wk+bk, V = x@Wv+bv, A = pos@W1 (no bias)
// ---------------------------------------------------------------------------
__global__ __launch_bounds__(256) void prep_kernel(
    const float* __restrict__ x, const float* __restrict__ pos,
    const float* __restrict__ Wq, const float* __restrict__ bq,
    const float* __restrict__ Wk, const float* __restrict__ bk,
    const float* __restrict__ Wv, const float* __restrict__ bv,
    const float* __restrict__ W1,
    float* __restrict__ Q, float* __restrict__ K, float* __restrict__ V,
    float* __restrict__ A)
{
    const int i = blockIdx.x, t = threadIdx.x;
    __shared__ float xs[IN_DIM];
    __shared__ float ps[3];
    if (t < IN_DIM) xs[t] = x[i * IN_DIM + t];
    if (t < 3) ps[t] = pos[i * 3 + t];
    __syncthreads();
    float q = bq[t], k = bk[t], v = bv[t];
#pragma unroll 8
    for (int kk = 0; kk < IN_DIM; ++kk) {
        const float xv = xs[kk];
        q += xv * Wq[kk * HID + t];
        k += xv * Wk[kk * HID + t];
        v += xv * Wv[kk * HID + t];
    }
    const float a = ps[0] * W1[t] + ps[1] * W1[HID + t] + ps[2] * W1[2 * HID + t];
    Q[i * HID + t] = q;
    K[i * HID + t] = k;
    V[i * HID + t] = v;
    A[i * HID + t] = a;
}

// ---------------------------------------------------------------------------
// fused main kernel: one block per query row i.
// Per j-tile (TJ=16): H1 -> H2 -> enc -> scores; then softmax, PV, Wo proj.
// ---------------------------------------------------------------------------
__global__ __launch_bounds__(256, 2) void fused_attn_kernel(
    const float* __restrict__ Qg, const float* __restrict__ Kg,
    const float* __restrict__ Vg, const float* __restrict__ Ag,
    const float* __restrict__ W2, const float* __restrict__ b1,
    const float* __restrict__ b2, const float* __restrict__ W3,
    const float* __restrict__ b3, const float* __restrict__ Wo,
    const float* __restrict__ bo, float* __restrict__ out)
{
    const int i = blockIdx.x;
    const int t = threadIdx.x;
    const int g = t >> 5;   // head / jj-group id (0..7)
    const int d = t & 31;   // lane within group

    __shared__ float h1T[HID][20];     // H1 transposed [k][jj]; reused as klds[16][264]
    __shared__ float h2s[TJ][260];     // H2 [jj][k]
    __shared__ float encs[TJ][33];     // enc [jj][d]
    __shared__ float slds[HEADS][N];   // scores then probs
    __shared__ float qs[HEADS * 33];   // Q row, per-head padded
    __shared__ float oa[HID];          // attention output row

    const float a_i = Ag[i * HID + t];
    const float b1t = b1[t];
    const float b2t = b2[t];
    const float b3t = b3[d];
    qs[g * 33 + d] = Qg[i * HID + t];
    float* klds = &h1T[0][0];          // aliased space, 16*264 <= 256*20
    __syncthreads();

    for (int tile = 0; tile < NT; ++tile) {
        const int j0 = tile * TJ;

        // ---- phase 1: H1 = relu(A[j] - A[i] + b1); prefetch K tile to regs
        float kv[TJ];
        float h1v[TJ];
#pragma unroll
        for (int jj = 0; jj < TJ; ++jj) {
            const float av = Ag[(j0 + jj) * HID + t];
            kv[jj] = Kg[(j0 + jj) * HID + t];
            h1v[jj] = relu_f(av - a_i + b1t);
        }
        *(float4*)&h1T[t][0]  = make_float4(h1v[0], h1v[1], h1v[2], h1v[3]);
        *(float4*)&h1T[t][4]  = make_float4(h1v[4], h1v[5], h1v[6], h1v[7]);
        *(float4*)&h1T[t][8]  = make_float4(h1v[8], h1v[9], h1v[10], h1v[11]);
        *(float4*)&h1T[t][12] = make_float4(h1v[12], h1v[13], h1v[14], h1v[15]);
        __syncthreads();

        // ---- phase 2: H2[jj][t] = relu(sum_k H1[jj][k] * W2[k][t] + b2[t])
        float acc[TJ];
#pragma unroll
        for (int jj = 0; jj < TJ; ++jj) acc[jj] = b2t;
        const float* w2p = W2 + t;
#pragma unroll 2
        for (int k = 0; k < HID; ++k) {
            const float w = w2p[k * HID];
            const float4 ha  = *(const float4*)&h1T[k][0];
            const float4 hb  = *(const float4*)&h1T[k][4];
            const float4 hc  = *(const float4*)&h1T[k][8];
            const float4 hd4 = *(const float4*)&h1T[k][12];
            acc[0]  += ha.x * w;  acc[1]  += ha.y * w;  acc[2]  += ha.z * w;  acc[3]  += ha.w * w;
            acc[4]  += hb.x * w;  acc[5]  += hb.y * w;  acc[6]  += hb.z * w;  acc[7]  += hb.w * w;
            acc[8]  += hc.x * w;  acc[9]  += hc.y * w;  acc[10] += hc.z * w;  acc[11] += hc.w * w;
            acc[12] += hd4.x * w; acc[13] += hd4.y * w; acc[14] += hd4.z * w; acc[15] += hd4.w * w;
        }
#pragma unroll
        for (int jj = 0; jj < TJ; ++jj) h2s[jj][t] = relu_f(acc[jj]);
        __syncthreads();   // all h1T reads done; h2s ready

        // write prefetched K tile into reused LDS (per-head pad 33)
#pragma unroll
        for (int jj = 0; jj < TJ; ++jj) klds[jj * 264 + g * 33 + d] = kv[jj];

        // ---- phase 3: enc[jj][d] = sum_k H2[jj][k] * W3[k][d] + b3[d]
        float e0 = b3t, e1 = b3t;
        const float* w3p = W3 + d;
#pragma unroll 4
        for (int k = 0; k < HID; k += 4) {
            const float4 hA = *(const float4*)&h2s[g][k];
            const float4 hB = *(const float4*)&h2s[g + 8][k];
            const float w30 = w3p[(k + 0) * HD];
            const float w31 = w3p[(k + 1) * HD];
            const float w32 = w3p[(k + 2) * HD];
            const float w33 = w3p[(k + 3) * HD];
            e0 += hA.x * w30 + hA.y * w31 + hA.z * w32 + hA.w * w33;
            e1 += hB.x * w30 + hB.y * w31 + hB.z * w32 + hB.w * w33;
        }
        encs[g][d] = e0;
        encs[g + 8][d] = e1;
        __syncthreads();   // enc + klds ready

        // ---- phase 4: scores[h][j0+jj] = q_h . (k_h + enc) / sqrt(HD)
        if (t < 128) {
            const int jj = t >> 3, h = t & 7;
            const float* qh = &qs[h * 33];
            const float* kr = &klds[jj * 264 + h * 33];
            const float* er = &encs[jj][0];
            float s = 0.f;
#pragma unroll
            for (int dd = 0; dd < HD; ++dd)
                s += qh[dd] * (kr[dd] + er[dd]);
            slds[h][j0 + jj] = s * 0.17677669529663687f;  // 1/sqrt(32)
        }
        __syncthreads();   // phase-4 reads done; next tile may overwrite h1T/klds
    }

    // ---- softmax per head (group g handles head g; 32 lanes per group)
    const float* srow = &slds[g][0];
    float m = -3.0e38f;
#pragma unroll 4
    for (int j = d; j < N; j += 32) m = fmaxf(m, srow[j]);
#pragma unroll
    for (int o = 16; o; o >>= 1) m = fmaxf(m, __shfl_xor(m, o));
    float ssum = 0.f;
#pragma unroll 4
    for (int j = d; j < N; j += 32) {
        const float p = __expf(srow[j] - m);
        slds[g][j] = p;
        ssum += p;
    }
#pragma unroll
    for (int o = 16; o; o >>= 1) ssum += __shfl_xor(ssum, o);
    const float inv_sum = 1.f / ssum;
    __syncthreads();   // all probs written

    // ---- PV: out_attn[i][t] = (1/sum_h) * sum_j p[h][j] * V[j][t], h = t>>5
    float o_acc = 0.f;
#pragma unroll 4
    for (int j = 0; j < N; ++j) o_acc += slds[g][j] * Vg[j * HID + t];
    oa[t] = o_acc * inv_sum;
    __syncthreads();

    // ---- final projection: out[i][t] = bo[t] + sum_k oa[k] * Wo[k][t]
    float r = bo[t];
    const float* wop = Wo + t;
#pragma unroll 4
    for (int k = 0; k < HID; k += 4) {
        const float4 ov = *(const float4*)&oa[k];
        r += ov.x * wop[(k + 0) * HID] + ov.y * wop[(k + 1) * HID]
           + ov.z * wop[(k + 2) * HID] + ov.w * wop[(k + 3) * HID];
    }
    out[i * HID + t] = r;
}

// ---------------------------------------------------------------------------
extern "C" void kernel_launch(void* const* d_in, const int* in_sizes, int n_in,
                              void* d_out, int out_size, void* d_ws, size_t ws_size,
                              hipStream_t stream)
{
    const float* x   = (const float*)d_in[0];
    const float* pos = (const float*)d_in[1];
    const float* Wq  = (const float*)d_in[2];
    const float* bq  = (const float*)d_in[3];
    const float* Wk  = (const float*)d_in[4];
    const float* bk  = (const float*)d_in[5];
    const float* Wv  = (const float*)d_in[6];
    const float* bv  = (const float*)d_in[7];
    const float* Wo  = (const float*)d_in[8];
    const float* bo  = (const float*)d_in[9];
    const float* W1  = (const float*)d_in[10];
    const float* b1  = (const float*)d_in[11];
    const float* W2  = (const float*)d_in[12];
    const float* b2  = (const float*)d_in[13];
    const float* W3  = (const float*)d_in[14];
    const float* b3  = (const float*)d_in[15];
    float* out = (float*)d_out;

    float* ws = (float*)d_ws;
    float* Q = ws;
    float* K = ws + (size_t)N * HID;
    float* V = ws + (size_t)2 * N * HID;
    float* A = ws + (size_t)3 * N * HID;

    prep_kernel<<<N, 256, 0, stream>>>(x, pos, Wq, bq, Wk, bk, Wv, bv, W1, Q, K, V, A);
    fused_attn_kernel<<<N, 256, 0, stream>>>(Q, K, V, A, W2, b1, b2, W3, b3, Wo, bo, out);
}

// Round 2
// 328.041 us; speedup vs baseline: 7.0312x; 7.0312x over previous
//
#include <hip/hip_runtime.h>
#include <math.h>

#define N 768
#define IN_DIM 128
#define HID 256
#define HEADS 8
#define HD 32
#define TJ 64
#define NT (N / TJ)
#define SCALE_INV 0.17677669529663687f  // 1/sqrt(32)

typedef short s16x8 __attribute__((ext_vector_type(8)));
typedef float f32x4 __attribute__((ext_vector_type(4)));

__device__ __forceinline__ unsigned short f2bf(float f) {
    unsigned u = __float_as_uint(f);
    u += 0x7FFF + ((u >> 16) & 1);
    return (unsigned short)(u >> 16);
}
__device__ __forceinline__ float bf2f(unsigned short s) {
    return __uint_as_float(((unsigned)s) << 16);
}

// ---------------------------------------------------------------------------
// prep: Q,K f32; A = pos@W1 f32; Vt = V^T in bf16 (row = hidden idx, col = j)
// ---------------------------------------------------------------------------
__global__ __launch_bounds__(256) void prep_kernel(
    const float* __restrict__ x, const float* __restrict__ pos,
    const float* __restrict__ Wq, const float* __restrict__ bq,
    const float* __restrict__ Wk, const float* __restrict__ bk,
    const float* __restrict__ Wv, const float* __restrict__ bv,
    const float* __restrict__ W1,
    float* __restrict__ Q, float* __restrict__ K,
    unsigned short* __restrict__ Vt, float* __restrict__ A)
{
    const int i = blockIdx.x, t = threadIdx.x;
    __shared__ float xs[IN_DIM];
    __shared__ float ps[3];
    if (t < IN_DIM) xs[t] = x[i * IN_DIM + t];
    if (t < 3) ps[t] = pos[i * 3 + t];
    __syncthreads();
    float q = bq[t], k = bk[t], v = bv[t];
#pragma unroll 8
    for (int kk = 0; kk < IN_DIM; ++kk) {
        const float xv = xs[kk];
        q += xv * Wq[kk * HID + t];
        k += xv * Wk[kk * HID + t];
        v += xv * Wv[kk * HID + t];
    }
    const float a = ps[0] * W1[t] + ps[1] * W1[HID + t] + ps[2] * W1[2 * HID + t];
    Q[i * HID + t] = q;
    K[i * HID + t] = k;
    Vt[(size_t)t * N + i] = f2bf(v);
    A[i * HID + t] = a;
}

// ---------------------------------------------------------------------------
// pack W2 into bf16 MFMA B-fragment order:
// w2f[((s*16+nt)*64+l)*8+e] = W2[k][n], k=32s+8(l>>4)+e, n=16nt+(l&15)
// ---------------------------------------------------------------------------
__global__ __launch_bounds__(256) void pack_w2_kernel(
    const float* __restrict__ W2, unsigned short* __restrict__ w2f)
{
    const int p = blockIdx.x * 256 + threadIdx.x;   // 65536 total
    const int e = p & 7, l = (p >> 3) & 63, nt = (p >> 9) & 15, s = p >> 13;
    const int k = 32 * s + 8 * (l >> 4) + e;
    const int n = 16 * nt + (l & 15);
    w2f[p] = f2bf(W2[k * HID + n]);
}

// ---------------------------------------------------------------------------
// per-i: S1[h][i][j] = q_i,h . k_j,h  (fp32), and
// w3q frags: w3q[h][k] = sum_d W3[k][d]*q[h][d] in B-fragment order (bf16)
// ---------------------------------------------------------------------------
__global__ __launch_bounds__(256) void s1_w3q_kernel(
    const float* __restrict__ Qg, const float* __restrict__ Kg,
    const float* __restrict__ W3,
    float* __restrict__ S1, unsigned short* __restrict__ w3qg)
{
    const int i = blockIdx.x, t = threadIdx.x;
    __shared__ float qrow[HID];
    qrow[t] = Qg[i * HID + t];
    __syncthreads();

    // ---- S1
    const int h = t & 7, jr = t >> 3;
    float4 qv[8];
#pragma unroll
    for (int d0 = 0; d0 < 8; ++d0) qv[d0] = *(const float4*)&qrow[h * HD + 4 * d0];
#pragma unroll 2
    for (int jb = 0; jb < 24; ++jb) {
        const int j = jb * 32 + jr;
        const float* kp = Kg + (size_t)j * HID + h * HD;
        float s = 0.f;
#pragma unroll
        for (int d0 = 0; d0 < 8; ++d0) {
            const float4 kv = *(const float4*)(kp + 4 * d0);
            s += qv[d0].x * kv.x + qv[d0].y * kv.y + qv[d0].z * kv.z + qv[d0].w * kv.w;
        }
        S1[(size_t)h * (N * N) + (size_t)i * N + j] = s;
    }

    // ---- w3q fragments
    const int l = t & 63, sp = t >> 6, lg = l >> 4, hh = l & 15;
#pragma unroll
    for (int ss = 0; ss < 2; ++ss) {
        const int s = 2 * sp + ss;
        s16x8 frag = {0, 0, 0, 0, 0, 0, 0, 0};
        if (hh < 8) {
#pragma unroll
            for (int e = 0; e < 8; ++e) {
                const int k = 32 * s + 8 * lg + e;
                const float* w3p = W3 + k * HD;
                float acc = 0.f;
#pragma unroll
                for (int d0 = 0; d0 < 32; d0 += 4) {
                    const float4 wv = *(const float4*)(w3p + d0);
                    acc += wv.x * qrow[hh * HD + d0] + wv.y * qrow[hh * HD + d0 + 1]
                         + wv.z * qrow[hh * HD + d0 + 2] + wv.w * qrow[hh * HD + d0 + 3];
                }
                frag[e] = (short)f2bf(acc);
            }
        }
        *(s16x8*)(w3qg + (size_t)i * 4096 + (size_t)(s * 64 + l) * 8) = frag;
    }
}

// ---------------------------------------------------------------------------
// fused main kernel: one block (4 waves) per query row i.
// ---------------------------------------------------------------------------
__global__ __launch_bounds__(256, 2) void fused_main_kernel(
    const float* __restrict__ Ag, const float* __restrict__ S1,
    const unsigned short* __restrict__ Vt, const unsigned short* __restrict__ w2fg,
    const unsigned short* __restrict__ w3qg,
    const float* __restrict__ b1, const float* __restrict__ b2,
    const float* __restrict__ Wo, const float* __restrict__ bo,
    float* __restrict__ out)
{
    const int i = blockIdx.x, t = threadIdx.x;
    const int w = t >> 6, l = t & 63;
    const int lg = l >> 4;        // quad group 0..3
    const int l15 = l & 15;

    __shared__ __align__(16) short h1f[4 * 8 * 64 * 8];   // 32 KB, A-frag order
    __shared__ __align__(16) short h2s[64 * 264];          // 33 KB, [j][k] pad 264
    __shared__ __align__(16) short w3qf[8 * 64 * 8];       // 8 KB, B-frag order
    __shared__ __align__(16) float slds[8 * 68];           // scores [h][jj] pad 68
    __shared__ float basek[HID];
    __shared__ float oa[HID];

    // ---------------- prolog
    basek[t] = b1[t] - Ag[(size_t)i * HID + t];
    {
        const int c0 = t, c1 = t + 256;   // 512 chunks of 8 shorts
        *(s16x8*)&w3qf[c0 * 8] = *(const s16x8*)(w3qg + (size_t)i * 4096 + (size_t)c0 * 8);
        *(s16x8*)&w3qf[c1 * 8] = *(const s16x8*)(w3qg + (size_t)i * 4096 + (size_t)c1 * 8);
    }
    float bias[4];
#pragma unroll
    for (int n = 0; n < 4; ++n) bias[n] = b2[64 * w + 16 * n + l15];

    float pv = 0.f, psum = 0.f, m_run = -3.0e38f;
    const int h = t >> 5, dl = t & 31;
    const unsigned short* vrow = Vt + (size_t)t * N;
    __syncthreads();

    for (int tile = 0; tile < NT; ++tile) {
        const int j0 = tile * TJ;

        // ---- phase A: H1 in A-fragment order
        const int jj = 16 * w + l15;
        float4 av[16];
        const float* ap = Ag + (size_t)(j0 + jj) * HID + 8 * lg;
#pragma unroll
        for (int s = 0; s < 8; ++s) {
            av[2 * s]     = *(const float4*)(ap + 32 * s);
            av[2 * s + 1] = *(const float4*)(ap + 32 * s + 4);
        }
#pragma unroll
        for (int s = 0; s < 8; ++s) {
            const float4 b0 = *(const float4*)&basek[32 * s + 8 * lg];
            const float4 b4 = *(const float4*)&basek[32 * s + 8 * lg + 4];
            s16x8 hv;
            hv[0] = (short)f2bf(fmaxf(av[2*s].x + b0.x, 0.f));
            hv[1] = (short)f2bf(fmaxf(av[2*s].y + b0.y, 0.f));
            hv[2] = (short)f2bf(fmaxf(av[2*s].z + b0.z, 0.f));
            hv[3] = (short)f2bf(fmaxf(av[2*s].w + b0.w, 0.f));
            hv[4] = (short)f2bf(fmaxf(av[2*s+1].x + b4.x, 0.f));
            hv[5] = (short)f2bf(fmaxf(av[2*s+1].y + b4.y, 0.f));
            hv[6] = (short)f2bf(fmaxf(av[2*s+1].z + b4.z, 0.f));
            hv[7] = (short)f2bf(fmaxf(av[2*s+1].w + b4.w, 0.f));
            *(s16x8*)&h1f[((w * 8 + s) * 64 + l) * 8] = hv;
        }
        // W2 B-fragments for this wave's n-slice (issued before barrier)
        s16x8 bfr[32];
#pragma unroll
        for (int s = 0; s < 8; ++s)
#pragma unroll
            for (int n = 0; n < 4; ++n)
                bfr[s * 4 + n] = *(const s16x8*)(w2fg + (size_t)(((s * 16 + 4 * w + n) * 64 + l)) * 8);
        __syncthreads();

        // ---- phase B: H2 = relu(H1@W2 + b2), 128 MFMAs/wave
#pragma unroll
        for (int mt = 0; mt < 4; ++mt) {
            s16x8 a[8];
#pragma unroll
            for (int s = 0; s < 8; ++s) a[s] = *(const s16x8*)&h1f[((mt * 8 + s) * 64 + l) * 8];
#pragma unroll
            for (int n = 0; n < 4; ++n) {
                f32x4 acc = {bias[n], bias[n], bias[n], bias[n]};
#pragma unroll
                for (int s = 0; s < 8; ++s)
                    acc = __builtin_amdgcn_mfma_f32_16x16x32_bf16(a[s], bfr[s * 4 + n], acc, 0, 0, 0);
                const int col = 64 * w + 16 * n + l15;
                const int jrow = 16 * mt + 4 * lg;
#pragma unroll
                for (int r = 0; r < 4; ++r)
                    h2s[(jrow + r) * 264 + col] = (short)f2bf(fmaxf(acc[r], 0.f));
            }
        }
        __syncthreads();

        // ---- phase C: score2 = H2 @ w3q (+S1), 8 MFMAs/wave
        float4 s1v = make_float4(0.f, 0.f, 0.f, 0.f);
        if (l15 < 8)
            s1v = *(const float4*)(S1 + (size_t)l15 * (N * N) + (size_t)i * N + j0 + 16 * w + 4 * lg);
        f32x4 acc2 = {0.f, 0.f, 0.f, 0.f};
#pragma unroll
        for (int s = 0; s < 8; ++s) {
            const s16x8 a2 = *(const s16x8*)&h2s[(16 * w + l15) * 264 + 32 * s + 8 * lg];
            const s16x8 wq = *(const s16x8*)&w3qf[(s * 64 + l) * 8];
            acc2 = __builtin_amdgcn_mfma_f32_16x16x32_bf16(a2, wq, acc2, 0, 0, 0);
        }
        if (l15 < 8) {
            float4 sc;
            sc.x = (acc2[0] + s1v.x) * SCALE_INV;
            sc.y = (acc2[1] + s1v.y) * SCALE_INV;
            sc.z = (acc2[2] + s1v.z) * SCALE_INV;
            sc.w = (acc2[3] + s1v.w) * SCALE_INV;
            *(float4*)&slds[l15 * 68 + 16 * w + 4 * lg] = sc;
        }
        __syncthreads();

        // ---- phase D: online softmax + PV
        float sc0 = slds[h * 68 + dl], sc1 = slds[h * 68 + dl + 32];
        float mtile = fmaxf(sc0, sc1);
#pragma unroll
        for (int o = 16; o; o >>= 1) mtile = fmaxf(mtile, __shfl_xor(mtile, o));
        const float mn = fmaxf(m_run, mtile);
        const float rescale = __expf(m_run - mn);
        pv *= rescale; psum *= rescale; m_run = mn;
        const unsigned short* vp = vrow + j0;
#pragma unroll
        for (int c = 0; c < 8; ++c) {
            const s16x8 vv = *(const s16x8*)(vp + c * 8);
            const float4 pa = *(const float4*)&slds[h * 68 + 8 * c];
            const float4 pb = *(const float4*)&slds[h * 68 + 8 * c + 4];
            float p;
            p = __expf(pa.x - mn); psum += p; pv += p * bf2f((unsigned short)vv[0]);
            p = __expf(pa.y - mn); psum += p; pv += p * bf2f((unsigned short)vv[1]);
            p = __expf(pa.z - mn); psum += p; pv += p * bf2f((unsigned short)vv[2]);
            p = __expf(pa.w - mn); psum += p; pv += p * bf2f((unsigned short)vv[3]);
            p = __expf(pb.x - mn); psum += p; pv += p * bf2f((unsigned short)vv[4]);
            p = __expf(pb.y - mn); psum += p; pv += p * bf2f((unsigned short)vv[5]);
            p = __expf(pb.z - mn); psum += p; pv += p * bf2f((unsigned short)vv[6]);
            p = __expf(pb.w - mn); psum += p; pv += p * bf2f((unsigned short)vv[7]);
        }
        __syncthreads();
    }

    // ---------------- epilogue: normalize + Wo projection
    oa[t] = pv / psum;
    __syncthreads();
    float r = bo[t];
    const float* wop = Wo + t;
#pragma unroll 4
    for (int k = 0; k < HID; k += 4) {
        const float4 ov = *(const float4*)&oa[k];
        r += ov.x * wop[(k + 0) * HID] + ov.y * wop[(k + 1) * HID]
           + ov.z * wop[(k + 2) * HID] + ov.w * wop[(k + 3) * HID];
    }
    out[(size_t)i * HID + t] = r;
}

// ---------------------------------------------------------------------------
extern "C" void kernel_launch(void* const* d_in, const int* in_sizes, int n_in,
                              void* d_out, int out_size, void* d_ws, size_t ws_size,
                              hipStream_t stream)
{
    const float* x   = (const float*)d_in[0];
    const float* pos = (const float*)d_in[1];
    const float* Wq  = (const float*)d_in[2];
    const float* bq  = (const float*)d_in[3];
    const float* Wk  = (const float*)d_in[4];
    const float* bk  = (const float*)d_in[5];
    const float* Wv  = (const float*)d_in[6];
    const float* bv  = (const float*)d_in[7];
    const float* Wo  = (const float*)d_in[8];
    const float* bo  = (const float*)d_in[9];
    const float* W1  = (const float*)d_in[10];
    const float* b1  = (const float*)d_in[11];
    const float* W2  = (const float*)d_in[12];
    const float* b2  = (const float*)d_in[13];
    const float* W3  = (const float*)d_in[14];
    const float* b3  = (const float*)d_in[15];  // folded out (softmax-invariant)
    (void)b3;
    float* out = (float*)d_out;

    char* ws = (char*)d_ws;
    float* Q  = (float*)(ws + 0);                       //  768*256 f32
    float* K  = (float*)(ws + 786432);                  //  768*256 f32
    float* A  = (float*)(ws + 1572864);                 //  768*256 f32
    float* S1 = (float*)(ws + 2359296);                 //  8*768*768 f32
    unsigned short* Vt   = (unsigned short*)(ws + 21233664);  // 256*768 bf16
    unsigned short* w2f  = (unsigned short*)(ws + 21626880);  // 65536 bf16
    unsigned short* w3qg = (unsigned short*)(ws + 21757952);  // 768*4096 bf16

    prep_kernel<<<N, 256, 0, stream>>>(x, pos, Wq, bq, Wk, bk, Wv, bv, W1, Q, K, Vt, A);
    pack_w2_kernel<<<256, 256, 0, stream>>>(W2, w2f);
    s1_w3q_kernel<<<N, 256, 0, stream>>>(Q, K, W3, S1, w3qg);
    fused_main_kernel<<<N, 256, 0, stream>>>(A, S1, Vt, w2f, w3qg, b1, b2, Wo, bo, out);
}